// Round 11
// baseline (191.747 us; speedup 1.0000x reference)
//
#include <hip/hip_runtime.h>
#include <stdint.h>

// EMA along contiguous T axis — wave-per-sequence streaming, plain-C++
// rotating register window (NO inline-asm memory ops).
//
// R8-R10 post-mortem: three correctness failures proved untracked asm
// loads/stores are unfixable here — the RA's hazard model can't see them
// (live-range splits / copies / reuse between issue and vmcnt retirement
// corrupt data in ways keep-alives don't reliably fix). Meanwhile the
// compiler's OWN waitcnt legalizer emits counted vmcnt(N) at first use —
// correct by construction. The only compiler failure ever observed was
// SCHEDULING: R4 sank loads to their use because the scheduler targeted
// 8 waves/SIMD (64-VGPR budget). Fix the motive, not the mechanism:
//   - __launch_bounds__(256, 4): 128-VGPR budget (4 waves/SIMD = 4
//     blocks/CU residency, which we want anyway) -> no pressure motive
//     to sink an 8-deep rotating window (~85 VGPR total).
//   - sched_group_barrier(VMEM_WRITE 0x40 / VMEM_READ 0x20, 1, 0) at each
//     group's store/refill slot pins the 1-store-1-load cadence without
//     fencing VALU/DS ILP. Advisory only — cannot affect correctness.
//
// Structure (decoupling experiment, still the theory under test): one wave
// owns one sequence; no LDS, no barriers, no inter-wave coupling; loads
// always 8 groups (~4k cycles) ahead of use.
//
// Math (re-derived and verified this round): lane l owns elems [4l,4l+3]
// of each 256-elem group. b_k = zero-state chain of lane's 4 elems;
// wave Kogge-Stone scan with ratio d^4 gives S_l; eb = S_{l-1};
// y_{4l+k} = b_k + d^{k+1}*(eb + d^{4l}*c); carry c <- d^256*c + S_63.
// 6000 = 23*256 + 112: tail group load-clamped (dup read), store-predicated
// (lanes 0..27).

constexpr int T_LEN = 6000;
constexpr int BLOCK = 256;

typedef float f32x4 __attribute__((ext_vector_type(4)));

__global__ __launch_bounds__(BLOCK, 4) void ema_kernel(
    const float* __restrict__ x, const float* __restrict__ init,
    const float* __restrict__ wptr, float* __restrict__ out, int nseq)
{
    const int lane = threadIdx.x & 63;
    const int wid  = threadIdx.x >> 6;
    const int seq  = blockIdx.x * 4 + wid;
    if (seq >= nseq) return;            // no barriers anywhere -> safe

    const float w  = fminf(fmaxf(wptr[0], 0.0f), 1.0f);
    const float d  = 1.0f - w;
    const float s0 = init[seq];

    const f32x4* __restrict__ xs = (const f32x4*)(x   + (size_t)seq * T_LEN);
    f32x4* __restrict__       os = (f32x4*)      (out + (size_t)seq * T_LEN);

    // ---- data-independent constants ----
    const float pw0 = d;
    const float pw1 = d * d;
    const float pw2 = pw1 * d;
    const float pw3 = pw2 * d;          // d^4
    float qp[6];                         // (d^4)^(2^k), k=0..5
    qp[0] = pw3;
    #pragma unroll
    for (int k = 1; k < 6; ++k) qp[k] = qp[k-1] * qp[k-1];
    const float Q = qp[5] * qp[5];       // d^256 (group carry ratio)
    float qlane = 1.0f;                  // d^(4*lane)
    #pragma unroll
    for (int k = 0; k < 6; ++k) if ((lane >> k) & 1) qlane *= qp[k];

    float c = s0;                        // running group-entry state
    float agg;                           // group aggregate (wave-uniform)
    f32x4 o;

    // tail group 23: granule 1472+lane valid for lanes 0..27; clamp others
    const int gt = (lane < 28) ? (1472 + lane) : 1499;

    // ---- prologue: fill the 8-deep window (groups 0..7) ----
    f32x4 r0 = xs[lane];
    f32x4 r1 = xs[lane +  64];
    f32x4 r2 = xs[lane + 128];
    f32x4 r3 = xs[lane + 192];
    f32x4 r4 = xs[lane + 256];
    f32x4 r5 = xs[lane + 320];
    f32x4 r6 = xs[lane + 384];
    f32x4 r7 = xs[lane + 448];

    // per-group math: 4-elem chain, 6-shfl ratio scan, fixup -> o, agg
    #define GRP_BODY(xg)                                                   \
        {                                                                  \
            float b0 = w * (xg).x;                                         \
            float b1 = fmaf(d, b0, w * (xg).y);                            \
            float b2 = fmaf(d, b1, w * (xg).z);                            \
            float b3 = fmaf(d, b2, w * (xg).w);                            \
            float b = b3;                                                  \
            _Pragma("unroll")                                              \
            for (int k = 0; k < 6; ++k) {                                  \
                float pb = __shfl_up(b, 1 << k, 64);                       \
                if (lane >= (1 << k)) b = fmaf(qp[k], pb, b);              \
            }                                                              \
            float eb = __shfl_up(b, 1, 64);                                \
            if (lane == 0) eb = 0.0f;                                      \
            agg = __shfl(b, 63, 64);                                       \
            const float sl = fmaf(qlane, c, eb);                           \
            o.x = fmaf(pw0, sl, b0);                                       \
            o.y = fmaf(pw1, sl, b1);                                       \
            o.z = fmaf(pw2, sl, b2);                                       \
            o.w = fmaf(pw3, sl, b3);                                       \
        }

    // steady-state group: compute, store, carry, refill window (+8)
    #define GRP_L(xg, G, GN) do {                                          \
        GRP_BODY(xg)                                                       \
        os[64 * (G) + lane] = o;                                           \
        __builtin_amdgcn_sched_group_barrier(0x40, 1, 0); /* 1 VMEM write */\
        c = fmaf(Q, c, agg);                                               \
        xg = xs[GN];                                                       \
        __builtin_amdgcn_sched_group_barrier(0x20, 1, 0); /* 1 VMEM read */ \
    } while (0)

    // drain-phase group: no refill
    #define GRP_N(xg, G) do {                                              \
        GRP_BODY(xg)                                                       \
        os[64 * (G) + lane] = o;                                           \
        __builtin_amdgcn_sched_group_barrier(0x40, 1, 0);                  \
        c = fmaf(Q, c, agg);                                               \
    } while (0)

    GRP_L(r0, 0,  lane + 512);   // g0  -> load g8
    GRP_L(r1, 1,  lane + 576);   // g1  -> g9
    GRP_L(r2, 2,  lane + 640);   // g2  -> g10
    GRP_L(r3, 3,  lane + 704);   // g3  -> g11
    GRP_L(r4, 4,  lane + 768);   // g4  -> g12
    GRP_L(r5, 5,  lane + 832);   // g5  -> g13
    GRP_L(r6, 6,  lane + 896);   // g6  -> g14
    GRP_L(r7, 7,  lane + 960);   // g7  -> g15
    GRP_L(r0, 8,  lane + 1024);  // g8  -> g16
    GRP_L(r1, 9,  lane + 1088);  // g9  -> g17
    GRP_L(r2, 10, lane + 1152);  // g10 -> g18
    GRP_L(r3, 11, lane + 1216);  // g11 -> g19
    GRP_L(r4, 12, lane + 1280);  // g12 -> g20
    GRP_L(r5, 13, lane + 1344);  // g13 -> g21
    GRP_L(r6, 14, lane + 1408);  // g14 -> g22
    GRP_L(r7, 15, gt);           // g15 -> g23 (clamped tail load)
    GRP_N(r0, 16);               // g16
    GRP_N(r1, 17);               // g17
    GRP_N(r2, 18);               // g18
    GRP_N(r3, 19);               // g19
    GRP_N(r4, 20);               // g20
    GRP_N(r5, 21);               // g21
    GRP_N(r6, 22);               // g22

    // tail group 23 (112 elems): predicated store, carry unused
    {
        GRP_BODY(r7)
        (void)agg;
        if (lane < 28) os[1472 + lane] = o;
    }

    #undef GRP_L
    #undef GRP_N
    #undef GRP_BODY
}

extern "C" void kernel_launch(void* const* d_in, const int* in_sizes, int n_in,
                              void* d_out, int out_size, void* d_ws, size_t ws_size,
                              hipStream_t stream) {
    const float* mag_spec = (const float*)d_in[0];
    const float* initial_state = (const float*)d_in[1];
    const float* weights = (const float*)d_in[2];
    float* out = (float*)d_out;

    const int nseq = in_sizes[1];       // 8*2*257 = 4112

    const int G = (nseq + 3) / 4;       // 4 independent waves per block
    ema_kernel<<<G, BLOCK, 0, stream>>>(mag_spec, initial_state, weights, out, nseq);
}

// Round 12
// 179.462 us; speedup vs baseline: 1.0684x; 1.0684x over previous
//
#include <hip/hip_runtime.h>
#include <stdint.h>

// EMA along contiguous T axis — R0's verified 60.5µs structure + ONE change:
// non-temporal output stores.
//
// R11 post-mortem: compiler sank the register window AGAIN (VGPR 52 despite
// launch_bounds(256,4)); asm pipelines are correctness-unsafe (R8-R10).
// Pipeline-structure attacks are exhausted: six different schedules all pin
// at 2.1-2.45 TB/s. The unmanipulated variable is the TRAFFIC: steady-state
// FETCH_SIZE=48.5MB means half the 98.7MB input re-fetches from HBM every
// dispatch — the 96MB output stream allocates in L3 and evicts it
// (98.7+96.4 MB ~= 195MB of live lines vs 256MB L3). nt stores bypass L3
// allocation for the output -> input stays fully L3-resident -> ~48MB (33%)
// of HBM traffic disappears.
//
// Everything else is byte-identical to the verified R0 kernel:
// one block per sequence, float4 LDS staging, per-thread 25-elem affine
// chains (stride 25 -> 2-way max bank aliasing, free), shfl scan of affine
// maps, re-run with correct incoming state, coalesced store.

constexpr int T_LEN = 6000;
constexpr int K_PER_THREAD = 25;                 // stride 25: conflict-free
constexpr int N_ACTIVE = T_LEN / K_PER_THREAD;   // 240
constexpr int BLOCK = 256;

typedef float f32x4 __attribute__((ext_vector_type(4)));

__global__ __launch_bounds__(BLOCK) void ema_kernel(
    const float* __restrict__ x,      // [NSEQ, T]
    const float* __restrict__ init,   // [NSEQ]
    const float* __restrict__ wptr,   // [1]
    float* __restrict__ out)          // [NSEQ, T]
{
    __shared__ float tile[T_LEN];
    __shared__ float waveA[4];
    __shared__ float waveB[4];

    const int seq = blockIdx.x;
    const int tid = threadIdx.x;
    const int lane = tid & 63;
    const int wid = tid >> 6;

    const float w = fminf(fmaxf(wptr[0], 0.0f), 1.0f);
    const float d = 1.0f - w;

    const float* xs = x + (size_t)seq * T_LEN;
    float* os = out + (size_t)seq * T_LEN;

    // ---- 1. coalesced float4 load into LDS (6000/4 = 1500 float4) ----
    {
        const f32x4* xs4 = (const f32x4*)xs;
        f32x4* tile4 = (f32x4*)tile;
        #pragma unroll
        for (int i = 0; i < (T_LEN / 4 + BLOCK - 1) / BLOCK; ++i) {
            int idx = tid + i * BLOCK;
            if (idx < T_LEN / 4) tile4[idx] = xs4[idx];
        }
    }
    __syncthreads();

    // ---- 2. per-thread affine map over its K elements: s_out = A*s_in + B ----
    float A = 1.0f, B = 0.0f;
    if (tid < N_ACTIVE) {
        const int base = tid * K_PER_THREAD;
        #pragma unroll
        for (int j = 0; j < K_PER_THREAD; ++j) {
            float xv = tile[base + j];
            B = fmaf(w, xv, d * B);
            A *= d;
        }
    }

    // ---- 3. inclusive shfl scan of affine maps within wave (width 64) ----
    float a = A, b = B;
    #pragma unroll
    for (int off = 1; off < 64; off <<= 1) {
        float pa = __shfl_up(a, off, 64);
        float pb = __shfl_up(b, off, 64);
        if (lane >= off) {
            // combine earlier (pa,pb) then current (a,b): s -> a*(pa*s+pb)+b
            b = fmaf(a, pb, b);
            a = a * pa;
        }
    }
    // wave aggregates
    if (lane == 63) { waveA[wid] = a; waveB[wid] = b; }
    __syncthreads();

    // exclusive prefix over earlier waves (serial over <=3 entries, all threads)
    float pA = 1.0f, pB = 0.0f;
    for (int i = 0; i < wid; ++i) {
        pB = fmaf(waveA[i], pB, waveB[i]);
        pA = waveA[i] * pA;
    }

    // lane-exclusive within wave (shift inclusive scan by 1)
    float ea = __shfl_up(a, 1, 64);
    float eb = __shfl_up(b, 1, 64);
    if (lane == 0) { ea = 1.0f; eb = 0.0f; }

    // total exclusive prefix for this thread: s -> ea*(pA*s+pB)+eb
    const float Aex = ea * pA;
    const float Bex = fmaf(ea, pB, eb);

    // ---- 4. re-run chunk with correct incoming state, write in place ----
    if (tid < N_ACTIVE) {
        const float s0 = init[seq];
        float acc = fmaf(Aex, s0, Bex);
        const int base = tid * K_PER_THREAD;
        #pragma unroll
        for (int j = 0; j < K_PER_THREAD; ++j) {
            acc = fmaf(w, tile[base + j], d * acc);
            tile[base + j] = acc;
        }
    }
    __syncthreads();

    // ---- 5. coalesced store — NON-TEMPORAL (bypass L3 allocation so the
    //         output stream stops evicting the L3-resident input) ----
    {
        f32x4* os4 = (f32x4*)os;
        const f32x4* tile4 = (const f32x4*)tile;
        #pragma unroll
        for (int i = 0; i < (T_LEN / 4 + BLOCK - 1) / BLOCK; ++i) {
            int idx = tid + i * BLOCK;
            if (idx < T_LEN / 4)
                __builtin_nontemporal_store(tile4[idx], &os4[idx]);
        }
    }
}

extern "C" void kernel_launch(void* const* d_in, const int* in_sizes, int n_in,
                              void* d_out, int out_size, void* d_ws, size_t ws_size,
                              hipStream_t stream) {
    const float* mag_spec = (const float*)d_in[0];
    const float* initial_state = (const float*)d_in[1];
    const float* weights = (const float*)d_in[2];
    float* out = (float*)d_out;

    const int nseq = in_sizes[1];  // 8*2*257 = 4112

    ema_kernel<<<nseq, BLOCK, 0, stream>>>(mag_spec, initial_state, weights, out);
}